// Round 2
// baseline (125.829 us; speedup 1.0000x reference)
//
#include <hip/hip_runtime.h>

// SLAYER SNN forward, MI355X. Round 15 (= R14 resubmitted; R14 bench died on
// container acquisition, not on the kernel — no counters were produced).
// vs R13: kf tail rewritten. scan2 now prefetches all 100 ls2 values into
//   registers (static unroll), runs the serial scan register-only, and fuses
//   the dense product directly into the scan loop (per-step 32-lane shfl_xor
//   reduce + 2 atomicAdds from lane 0, gated by __ballot(s!=0) -> skip keeps
//   out at k0's zero, exact). Deletes the LDS spike write-back and the 7-pass
//   dense re-read that ran on a single wave (~48% of kf time per occupancy
//   math: 12.5%*f + 3.1%*(1-f) = 8.0% -> f=0.52).
// Also: XCD-aware (n,qtr) swizzle -- n=(bid&7)*8+(bid>>5), qtr=(bid>>3)&3 --
//   bijective; the 4 qtr siblings of each n now share one XCD's L2 for their
//   identical u1 slice (FETCH_SIZE was ~2x u1 with the old bid>>2 mapping).
// k0 (fold+zero out) and k1 (R9 conv1) unchanged.

#define DECAY 0.9048374180359595f   // exp(-1/10)

#define BAR_LGKM() asm volatile("s_waitcnt lgkmcnt(0)\n\ts_barrier" ::: "memory")
#define FENCE_LGKM() asm volatile("s_waitcnt lgkmcnt(0)" ::: "memory")

// ---------------- k0: fold weights + zero out ----------------
// wl1[(cin*8 + e)*32 + c*8 + f]; wl2[c2*68 + cin*16 + e*4 + f]
__global__ __launch_bounds__(128) void k0_fold(const float* __restrict__ w1,
        const float* __restrict__ w2, const float* __restrict__ wp1,
        const float* __restrict__ wp2, float* __restrict__ wl1,
        float* __restrict__ wl2, float* __restrict__ out) {
    const int tid = threadIdx.x;
    out[blockIdx.x * 128 + tid] = 0.f;
    if (blockIdx.x != 0) return;
    const float p1 = wp1[0], p2 = wp2[0];
    for (int idx = tid; idx < 512; idx += 128) {
        const int f = idx & 7, c = (idx >> 3) & 3, e = (idx >> 5) & 7, cin = idx >> 8;
        const int cc = c * 2 + cin;
        int alo = e - 3; if (alo < 0) alo = 0;
        int ahi = e;     if (ahi > 4) ahi = 4;
        int blo = f - 3; if (blo < 0) blo = 0;
        int bhi = f;     if (bhi > 4) bhi = 4;
        float s = 0.f;
        for (int a = alo; a <= ahi; ++a)
            for (int b = blo; b <= bhi; ++b)
                s += w1[cc * 25 + a * 5 + b];
        wl1[(cin * 8 + e) * 32 + c * 8 + f] = s * p1;
    }
    for (int idx = tid; idx < 512; idx += 128) {
        const int c2 = idx & 7, f = (idx >> 3) & 3, e = (idx >> 5) & 3, cin = idx >> 7;
        int alo = e - 1; if (alo < 0) alo = 0;
        int ahi = e;     if (ahi > 2) ahi = 2;
        int blo = f - 1; if (blo < 0) blo = 0;
        int bhi = f;     if (bhi > 2) bhi = 2;
        float s = 0.f;
        for (int aa = alo; aa <= ahi; ++aa)
            for (int bb = blo; bb <= bhi; ++bb)
                s += w2[((c2 * 4 + cin) * 3 + aa) * 3 + bb];
        wl2[c2 * 68 + cin * 16 + e * 4 + f] = s * p2;
    }
}

// ---------------- k1: conv1+pool1, 8x8-tap stride-4 (R9, unchanged) ----------------
__global__ __launch_bounds__(64) void k1(const float* __restrict__ x,
        const float* __restrict__ wg, float* __restrict__ u1) {
    __shared__ __align__(16) float xs[2 * 1296];
    __shared__ __align__(16) float wl[512];
    const int lane = threadIdx.x;
    const int frame = blockIdx.x;                  // = n*100 + t (x is n-major)
    const int n = frame / 100, t = frame % 100;

    *(float4*)(wl + 4 * lane)       = *(const float4*)(wg + 4 * lane);
    *(float4*)(wl + 256 + 4 * lane) = *(const float4*)(wg + 256 + 4 * lane);

    #pragma unroll
    for (int m0 = 0; m0 < 128; m0 += 64) {
        const int m = m0 + lane;
        if (m < 72) {
            const int cin = m / 36, rem = m % 36;
            const int rr = rem / 9, q4 = rem % 9;
            const int pr = (rr == 0) ? 0 : (rr == 1) ? 9 : (rr == 2) ? 26 : 35;
            *(float4*)(xs + cin * 1296 + pr * 36 + q4 * 4) = make_float4(0.f, 0.f, 0.f, 0.f);
        }
    }
    #pragma unroll
    for (int m0 = 0; m0 < 192; m0 += 64) {
        const int m = m0 + lane;
        if (m < 144) {
            const int cin = m / 72, rem = m % 72;
            const int side = rem & 1, pr = rem >> 1;
            *(float2*)(xs + cin * 1296 + pr * 36 + side * 34) = make_float2(0.f, 0.f);
        }
    }
    const float4* xg = (const float4*)(x + (size_t)frame * 2048);
    #pragma unroll
    for (int q = 0; q < 8; ++q) {
        const int m = q * 64 + lane;
        const float4 v = xg[m];
        const int li = 4 * m;
        const int cin = li >> 10, row = (li >> 5) & 31, col = li & 31;
        const int r = row + 2;
        const int pr = (r & 3) * 9 + (r >> 2);
        float* d = xs + cin * 1296 + pr * 36 + col + 2;
        *(float2*)(d)     = make_float2(v.x, v.y);
        *(float2*)(d + 2) = make_float2(v.z, v.w);
    }
    FENCE_LGKM();

    const int cp = lane >> 5;
    const int i  = (lane >> 2) & 7;
    const int jh = (lane >> 1) & 1;
    const int eh = lane & 1;

    float acc[2][4] = {{0.f, 0.f, 0.f, 0.f}, {0.f, 0.f, 0.f, 0.f}};
    const float* tb = xs + (i + eh) * 36 + jh * 16;
    #pragma unroll
    for (int cin = 0; cin < 2; ++cin) {
        #pragma unroll
        for (int et = 0; et < 4; ++et) {
            const int ro = cin * 1296 + et * 9 * 36;
            float xr[20];
            #pragma unroll
            for (int b = 0; b < 5; ++b)
                *(float4*)(xr + 4 * b) = *(const float4*)(tb + ro + 4 * b);
            float wv[16];
            const float* wp = wl + (cin * 8 + eh * 4 + et) * 32 + cp * 16;
            #pragma unroll
            for (int q = 0; q < 4; ++q)
                *(float4*)(wv + 4 * q) = *(const float4*)(wp + 4 * q);
            #pragma unroll
            for (int cl = 0; cl < 2; ++cl) {
                #pragma unroll
                for (int jj = 0; jj < 4; ++jj) {
                    const int o = 4 * jj;
                    acc[cl][jj] += xr[o]*wv[cl*8]     + xr[o+1]*wv[cl*8+1]
                                 + xr[o+2]*wv[cl*8+2] + xr[o+3]*wv[cl*8+3]
                                 + xr[o+4]*wv[cl*8+4] + xr[o+5]*wv[cl*8+5]
                                 + xr[o+6]*wv[cl*8+6] + xr[o+7]*wv[cl*8+7];
                }
            }
        }
    }
    #pragma unroll
    for (int cl = 0; cl < 2; ++cl)
        #pragma unroll
        for (int jj = 0; jj < 4; ++jj)
            acc[cl][jj] += __shfl_xor(acc[cl][jj], 1);

    const float o0 = eh ? acc[1][0] : acc[0][0];
    const float o1 = eh ? acc[1][1] : acc[0][1];
    const float o2 = eh ? acc[1][2] : acc[0][2];
    const float o3 = eh ? acc[1][3] : acc[0][3];
    *(float4*)(u1 + (size_t)t * 16384 + n * 256 + (2 * cp + eh) * 64 + i * 8 + jh * 4) =
        make_float4(o0, o1, o2, o3);
}

// ---------------- kf: fused scan1 + conv2(qtr) + scan2 + dense ----------------
// grid 256 x 256. XCD swizzle: n = (bid&7)*8 + (bid>>5), qtr = (bid>>3)&3
// -> the 4 qtr siblings of each n land on one XCD (dispatch ~ bid%8) and
// share its L2 for their identical u1 slice.
// ls1: 100 slots x 260 floats (104 KB); ls2: 100 x 36 (P2 -> tail transpose).
// Tail: wave0 lanes 0..31 prefetch ls2 column into regs, run scan2 register-
// only, and fuse dense: per step p = s*w per cell-lane, 5-step shfl_xor
// reduce over 32 lanes, lane0 atomicAdds out[n,t,0/1]. __ballot gate skips
// all-zero steps (out already zeroed by k0 -> exact).
__global__ __launch_bounds__(256) void kf(const float* __restrict__ u1,
        const float* __restrict__ wl2g, const float* __restrict__ lw,
        float* __restrict__ out) {
    __shared__ __align__(16) float ls1[100 * 260];  // 104 KB
    __shared__ __align__(16) float ls2[100 * 36];   // 14.4 KB
    const int tid = threadIdx.x;
    const int bid = blockIdx.x;
    const int n = (bid & 7) * 8 + (bid >> 5);       // XCD-aware, bijective
    const int qtr = (bid >> 3) & 3;
    const int wave = tid >> 6, l64 = tid & 63;
    const float a = DECAY;

    const float* up = u1 + n * 256 + tid;

    // P2 mapping: thread = (sub, c2l, i2, jhp); 2 j-outputs (j = 2jhp, 2jhp+1)
    const int sub = tid >> 4, l16 = tid & 15;
    const int c2l = l16 >> 3, i2 = (l16 >> 1) & 3, jhp = l16 & 1;
    const int c2g = qtr * 2 + c2l;

    float4 wreg[16];   // [cin*4+e] = folded taps f0..3
    {
        const float* wbase = wl2g + c2g * 68;
        #pragma unroll
        for (int q = 0; q < 16; ++q)
            wreg[q] = *(const float4*)(wbase + (q >> 2) * 16 + (q & 3) * 4);
    }

    // dense weights for the fused tail: lane (l64&31) = cell (c2l*16+i2*4+j)
    const int cell = l64 & 31;
    const float w0 = lw[qtr * 32 + cell];
    const float w1 = lw[128 + qtr * 32 + cell];

    // --- P1: load all 100 u (coalesced, pipelined), scan1, publish ---
    float vbuf[100];
    #pragma unroll
    for (int k = 0; k < 100; ++k) vbuf[k] = up[(size_t)k * 16384];
    {
        float psp = 0.f, rr = 0.f;
        #pragma unroll
        for (int k = 0; k < 100; ++k) {
            psp = a * psp + vbuf[k];
            const float vv = psp - rr;
            const float s = (vv >= 1.f) ? 1.f : 0.f;
            rr = a * (rr + s);
            ls1[k * 260 + tid] = s;
        }
    }
    BAR_LGKM();

    // --- P2: conv2, 7 predicated passes x 16 slots ---
    #pragma unroll 1
    for (int pass = 0; pass < 7; ++pass) {
        const int slot = sub + 16 * pass;
        if (slot < 100) {
            const float* sb = ls1 + slot * 260;
            float acc0 = 0.f, acc1 = 0.f;
            #pragma unroll
            for (int cin = 0; cin < 4; ++cin) {
                #pragma unroll
                for (int e = 0; e < 4; ++e) {
                    const int ri = 2 * i2 + e - 1;            // input row, -1..8
                    const int rc = (ri < 0) ? 0 : (ri > 7 ? 7 : ri);
                    const bool rok = (ri >= 0) && (ri <= 7);
                    float rr8[8];
                    const float* rp = sb + cin * 64 + rc * 8;
                    *(float4*)(rr8)     = *(const float4*)(rp);
                    *(float4*)(rr8 + 4) = *(const float4*)(rp + 4);
                    // xr matches R12's pad reads: jhp=0 -> {0,r0..r4}; jhp=1 -> {r3..r7,0}
                    float xr[6];
                    xr[0] = jhp ? rr8[3] : 0.0f;
                    xr[1] = jhp ? rr8[4] : rr8[0];
                    xr[2] = jhp ? rr8[5] : rr8[1];
                    xr[3] = jhp ? rr8[6] : rr8[2];
                    xr[4] = jhp ? rr8[7] : rr8[3];
                    xr[5] = jhp ? 0.0f   : rr8[4];
                    if (!rok) {
                        #pragma unroll
                        for (int m = 0; m < 6; ++m) xr[m] = 0.0f;
                    }
                    const float4 wf = wreg[cin * 4 + e];
                    acc0 += xr[0] * wf.x; acc0 += xr[1] * wf.y;
                    acc0 += xr[2] * wf.z; acc0 += xr[3] * wf.w;
                    acc1 += xr[2] * wf.x; acc1 += xr[3] * wf.y;
                    acc1 += xr[4] * wf.z; acc1 += xr[5] * wf.w;
                }
            }
            *(float2*)(ls2 + slot * 36 + c2l * 16 + i2 * 4 + 2 * jhp) =
                make_float2(acc0, acc1);
        }
    }
    BAR_LGKM();

    // --- tail (wave0, lanes 0..31): register scan2 + fused dense ---
    if (wave == 0 && l64 < 32) {
        // prefetch the full 100-step column for this cell (static indices ->
        // stays in VGPRs; reuses vbuf's dead range)
        float ub[100];
        #pragma unroll
        for (int k = 0; k < 100; ++k) ub[k] = ls2[k * 36 + l64];
        float psp2 = 0.f, rr2 = 0.f;
        #pragma unroll
        for (int k = 0; k < 100; ++k) {
            psp2 = a * psp2 + ub[k];
            const float vv = psp2 - rr2;
            const float s = (vv >= 1.f) ? 1.f : 0.f;
            rr2 = a * (rr2 + s);
            const unsigned long long b = __ballot(s != 0.f);
            if (b) {
                float p0 = s * w0, p1 = s * w1;
                #pragma unroll
                for (int m = 16; m >= 1; m >>= 1) {
                    p0 += __shfl_xor(p0, m);
                    p1 += __shfl_xor(p1, m);
                }
                if (l64 == 0) {
                    atomicAdd(&out[n * 200 + k * 2],     p0);
                    atomicAdd(&out[n * 200 + k * 2 + 1], p1);
                }
            }
        }
    }
}

extern "C" void kernel_launch(void* const* d_in, const int* in_sizes, int n_in,
                              void* d_out, int out_size, void* d_ws, size_t ws_size,
                              hipStream_t stream) {
    const float* x   = (const float*)d_in[0];
    const float* w1  = (const float*)d_in[1];
    const float* w2  = (const float*)d_in[2];
    const float* lw  = (const float*)d_in[3];
    const float* wp1 = (const float*)d_in[4];
    const float* wp2 = (const float*)d_in[5];

    float* u1  = (float*)d_ws;           // 1,638,400 floats
    float* wl1 = u1 + 1638400;           //       512 floats
    float* wl2 = wl1 + 512;              //       544 floats
    float* out = (float*)d_out;          // (64,100,2) = 12800 floats

    k0_fold<<<100, 128, 0, stream>>>(w1, w2, wp1, wp2, wl1, wl2, out);
    k1<<<6400, 64, 0, stream>>>(x, wl1, u1);
    kf<<<256, 256, 0, stream>>>(u1, wl2, lw, out);
}

// Round 3
// 117.838 us; speedup vs baseline: 1.0678x; 1.0678x over previous
//
#include <hip/hip_runtime.h>

// SLAYER SNN forward, MI355X. Round 16.
// vs R15: kf restructured for occupancy. Spikes stored as f16 (0/1 exact ->
//   conv2 FMA tree bit-identical): ls1 104 KB -> 52.8 KB. qtr split -> oct
//   split (grid 512, 1 c2 channel/block): LDS 61 KB -> 2 blocks/CU, 8
//   waves/CU (was 1 block, 4 waves -> 1 wave/SIMD, everything latency-naked).
//   P2 row read = one ds_read_b128 of 8 halfs + cvt (was 2x b128 f32).
//   Tail: wave0 lanes 0..15 register-scan2 (prefetch ub[100], store-only
//   publish), then ALL 256 threads do the 200 (t,o) dot products from ls2
//   rows (4x b128 + 16 FMA + 1 atomicAdd) -- replaces R14/15's 100-step
//   dependent shuffle-tree tail. oct-siblings share an XCD (bid%8 fixed per
//   n) -> u1 slice L2-resident despite 8x re-read (819 KB/XCD < 4 MB L2).
// k0 (fold+zero out) and k1 (R9 conv1) unchanged.

#define DECAY 0.9048374180359595f   // exp(-1/10)

#define BAR_LGKM() asm volatile("s_waitcnt lgkmcnt(0)\n\ts_barrier" ::: "memory")
#define FENCE_LGKM() asm volatile("s_waitcnt lgkmcnt(0)" ::: "memory")

typedef __attribute__((ext_vector_type(8))) _Float16 half8;

// ---------------- k0: fold weights + zero out ----------------
// wl1[(cin*8 + e)*32 + c*8 + f]; wl2[c2*68 + cin*16 + e*4 + f]
__global__ __launch_bounds__(128) void k0_fold(const float* __restrict__ w1,
        const float* __restrict__ w2, const float* __restrict__ wp1,
        const float* __restrict__ wp2, float* __restrict__ wl1,
        float* __restrict__ wl2, float* __restrict__ out) {
    const int tid = threadIdx.x;
    out[blockIdx.x * 128 + tid] = 0.f;
    if (blockIdx.x != 0) return;
    const float p1 = wp1[0], p2 = wp2[0];
    for (int idx = tid; idx < 512; idx += 128) {
        const int f = idx & 7, c = (idx >> 3) & 3, e = (idx >> 5) & 7, cin = idx >> 8;
        const int cc = c * 2 + cin;
        int alo = e - 3; if (alo < 0) alo = 0;
        int ahi = e;     if (ahi > 4) ahi = 4;
        int blo = f - 3; if (blo < 0) blo = 0;
        int bhi = f;     if (bhi > 4) bhi = 4;
        float s = 0.f;
        for (int a = alo; a <= ahi; ++a)
            for (int b = blo; b <= bhi; ++b)
                s += w1[cc * 25 + a * 5 + b];
        wl1[(cin * 8 + e) * 32 + c * 8 + f] = s * p1;
    }
    for (int idx = tid; idx < 512; idx += 128) {
        const int c2 = idx & 7, f = (idx >> 3) & 3, e = (idx >> 5) & 3, cin = idx >> 7;
        int alo = e - 1; if (alo < 0) alo = 0;
        int ahi = e;     if (ahi > 2) ahi = 2;
        int blo = f - 1; if (blo < 0) blo = 0;
        int bhi = f;     if (bhi > 2) bhi = 2;
        float s = 0.f;
        for (int aa = alo; aa <= ahi; ++aa)
            for (int bb = blo; bb <= bhi; ++bb)
                s += w2[((c2 * 4 + cin) * 3 + aa) * 3 + bb];
        wl2[c2 * 68 + cin * 16 + e * 4 + f] = s * p2;
    }
}

// ---------------- k1: conv1+pool1, 8x8-tap stride-4 (R9, unchanged) ----------------
__global__ __launch_bounds__(64) void k1(const float* __restrict__ x,
        const float* __restrict__ wg, float* __restrict__ u1) {
    __shared__ __align__(16) float xs[2 * 1296];
    __shared__ __align__(16) float wl[512];
    const int lane = threadIdx.x;
    const int frame = blockIdx.x;                  // = n*100 + t (x is n-major)
    const int n = frame / 100, t = frame % 100;

    *(float4*)(wl + 4 * lane)       = *(const float4*)(wg + 4 * lane);
    *(float4*)(wl + 256 + 4 * lane) = *(const float4*)(wg + 256 + 4 * lane);

    #pragma unroll
    for (int m0 = 0; m0 < 128; m0 += 64) {
        const int m = m0 + lane;
        if (m < 72) {
            const int cin = m / 36, rem = m % 36;
            const int rr = rem / 9, q4 = rem % 9;
            const int pr = (rr == 0) ? 0 : (rr == 1) ? 9 : (rr == 2) ? 26 : 35;
            *(float4*)(xs + cin * 1296 + pr * 36 + q4 * 4) = make_float4(0.f, 0.f, 0.f, 0.f);
        }
    }
    #pragma unroll
    for (int m0 = 0; m0 < 192; m0 += 64) {
        const int m = m0 + lane;
        if (m < 144) {
            const int cin = m / 72, rem = m % 72;
            const int side = rem & 1, pr = rem >> 1;
            *(float2*)(xs + cin * 1296 + pr * 36 + side * 34) = make_float2(0.f, 0.f);
        }
    }
    const float4* xg = (const float4*)(x + (size_t)frame * 2048);
    #pragma unroll
    for (int q = 0; q < 8; ++q) {
        const int m = q * 64 + lane;
        const float4 v = xg[m];
        const int li = 4 * m;
        const int cin = li >> 10, row = (li >> 5) & 31, col = li & 31;
        const int r = row + 2;
        const int pr = (r & 3) * 9 + (r >> 2);
        float* d = xs + cin * 1296 + pr * 36 + col + 2;
        *(float2*)(d)     = make_float2(v.x, v.y);
        *(float2*)(d + 2) = make_float2(v.z, v.w);
    }
    FENCE_LGKM();

    const int cp = lane >> 5;
    const int i  = (lane >> 2) & 7;
    const int jh = (lane >> 1) & 1;
    const int eh = lane & 1;

    float acc[2][4] = {{0.f, 0.f, 0.f, 0.f}, {0.f, 0.f, 0.f, 0.f}};
    const float* tb = xs + (i + eh) * 36 + jh * 16;
    #pragma unroll
    for (int cin = 0; cin < 2; ++cin) {
        #pragma unroll
        for (int et = 0; et < 4; ++et) {
            const int ro = cin * 1296 + et * 9 * 36;
            float xr[20];
            #pragma unroll
            for (int b = 0; b < 5; ++b)
                *(float4*)(xr + 4 * b) = *(const float4*)(tb + ro + 4 * b);
            float wv[16];
            const float* wp = wl + (cin * 8 + eh * 4 + et) * 32 + cp * 16;
            #pragma unroll
            for (int q = 0; q < 4; ++q)
                *(float4*)(wv + 4 * q) = *(const float4*)(wp + 4 * q);
            #pragma unroll
            for (int cl = 0; cl < 2; ++cl) {
                #pragma unroll
                for (int jj = 0; jj < 4; ++jj) {
                    const int o = 4 * jj;
                    acc[cl][jj] += xr[o]*wv[cl*8]     + xr[o+1]*wv[cl*8+1]
                                 + xr[o+2]*wv[cl*8+2] + xr[o+3]*wv[cl*8+3]
                                 + xr[o+4]*wv[cl*8+4] + xr[o+5]*wv[cl*8+5]
                                 + xr[o+6]*wv[cl*8+6] + xr[o+7]*wv[cl*8+7];
                }
            }
        }
    }
    #pragma unroll
    for (int cl = 0; cl < 2; ++cl)
        #pragma unroll
        for (int jj = 0; jj < 4; ++jj)
            acc[cl][jj] += __shfl_xor(acc[cl][jj], 1);

    const float o0 = eh ? acc[1][0] : acc[0][0];
    const float o1 = eh ? acc[1][1] : acc[0][1];
    const float o2 = eh ? acc[1][2] : acc[0][2];
    const float o3 = eh ? acc[1][3] : acc[0][3];
    *(float4*)(u1 + (size_t)t * 16384 + n * 256 + (2 * cp + eh) * 64 + i * 8 + jh * 4) =
        make_float4(o0, o1, o2, o3);
}

// ---------------- kf: fused scan1 + conv2(oct) + scan2 + dense ----------------
// grid 512 x 256: oct = (bid>>3)&7, n = (bid&7)*8 + (bid>>6)  (bijective;
// the 8 oct siblings of each n share bid%8 -> one XCD's L2 for the u1 slice).
// ls1h: 100 slots x 264 halfs (52.8 KB, row 528 B = 33x16 -> b128-aligned).
// ls2 : 100 slots x 20 floats (8 KB, row 80 B -> b128-aligned); cells [i*4+j].
__global__ __launch_bounds__(256, 2) void kf(const float* __restrict__ u1,
        const float* __restrict__ wl2g, const float* __restrict__ lw,
        float* __restrict__ out) {
    __shared__ __align__(16) _Float16 ls1h[100 * 264];  // 52.8 KB
    __shared__ __align__(16) float    ls2[100 * 20];    //  8.0 KB
    const int tid = threadIdx.x;
    const int bid = blockIdx.x;
    const int n   = (bid & 7) * 8 + (bid >> 6);   // XCD-aware, bijective
    const int oct = (bid >> 3) & 7;               // c2 channel
    const int wave = tid >> 6, l64 = tid & 63;
    const float a = DECAY;

    const float* up = u1 + n * 256 + tid;

    // P2 mapping: thread = (sub, i2, jhp); 8 threads/slot, 32 slots/pass
    const int sub = tid >> 3, l8 = tid & 7;
    const int i2 = l8 >> 1, jhp = l8 & 1;

    float4 wreg[16];   // [cin*4+e] = folded taps f0..3 for channel oct
    {
        const float* wbase = wl2g + oct * 68;
        #pragma unroll
        for (int q = 0; q < 16; ++q)
            wreg[q] = *(const float4*)(wbase + (q >> 2) * 16 + (q & 3) * 4);
    }

    // --- P1: load all 100 u (coalesced, pipelined), scan1, publish f16 ---
    float vbuf[100];
    #pragma unroll
    for (int k = 0; k < 100; ++k) vbuf[k] = up[(size_t)k * 16384];
    {
        float psp = 0.f, rr = 0.f;
        #pragma unroll
        for (int k = 0; k < 100; ++k) {
            psp = a * psp + vbuf[k];
            const float vv = psp - rr;
            const float s = (vv >= 1.f) ? 1.f : 0.f;
            rr = a * (rr + s);
            ls1h[k * 264 + tid] = (_Float16)s;   // 0/1 exact in f16
        }
    }
    BAR_LGKM();

    // --- P2: conv2 (1 channel), 4 predicated passes x 32 slots ---
    #pragma unroll 1
    for (int pass = 0; pass < 4; ++pass) {
        const int slot = sub + 32 * pass;
        if (slot < 100) {
            const _Float16* sb = ls1h + slot * 264;
            float acc0 = 0.f, acc1 = 0.f;
            #pragma unroll
            for (int cin = 0; cin < 4; ++cin) {
                #pragma unroll
                for (int e = 0; e < 4; ++e) {
                    const int ri = 2 * i2 + e - 1;            // input row, -1..8
                    const int rc = (ri < 0) ? 0 : (ri > 7 ? 7 : ri);
                    const bool rok = (ri >= 0) && (ri <= 7);
                    const half8 hv = *(const half8*)(sb + cin * 64 + rc * 8);
                    float rr8[8];
                    #pragma unroll
                    for (int m = 0; m < 8; ++m) rr8[m] = (float)hv[m];
                    // xr matches pad reads: jhp=0 -> {0,r0..r4}; jhp=1 -> {r3..r7,0}
                    float xr[6];
                    xr[0] = jhp ? rr8[3] : 0.0f;
                    xr[1] = jhp ? rr8[4] : rr8[0];
                    xr[2] = jhp ? rr8[5] : rr8[1];
                    xr[3] = jhp ? rr8[6] : rr8[2];
                    xr[4] = jhp ? rr8[7] : rr8[3];
                    xr[5] = jhp ? 0.0f   : rr8[4];
                    if (!rok) {
                        #pragma unroll
                        for (int m = 0; m < 6; ++m) xr[m] = 0.0f;
                    }
                    const float4 wf = wreg[cin * 4 + e];
                    acc0 += xr[0] * wf.x; acc0 += xr[1] * wf.y;
                    acc0 += xr[2] * wf.z; acc0 += xr[3] * wf.w;
                    acc1 += xr[2] * wf.x; acc1 += xr[3] * wf.y;
                    acc1 += xr[4] * wf.z; acc1 += xr[5] * wf.w;
                }
            }
            // cell index within channel = i2*4 + j  (j = 2jhp, 2jhp+1)
            *(float2*)(ls2 + slot * 20 + i2 * 4 + 2 * jhp) =
                make_float2(acc0, acc1);
        }
    }
    BAR_LGKM();

    // --- scan2: wave0 lanes 0..15 (one per cell), register-resident ---
    if (wave == 0 && l64 < 16) {
        float ub[100];
        #pragma unroll
        for (int k = 0; k < 100; ++k) ub[k] = ls2[k * 20 + l64];
        float psp2 = 0.f, rr2 = 0.f;
        #pragma unroll
        for (int k = 0; k < 100; ++k) {
            psp2 = a * psp2 + ub[k];
            const float vv = psp2 - rr2;
            const float s = (vv >= 1.f) ? 1.f : 0.f;
            rr2 = a * (rr2 + s);
            ls2[k * 20 + l64] = s;     // store-only publish (no RMW chain)
        }
    }
    BAR_LGKM();

    // --- dense: all waves; thread (t,o) dots 16 spikes x 16 weights ---
    if (tid < 200) {
        const int t = tid >> 1, o = tid & 1;
        const float* srow = ls2 + t * 20;
        const float* wrow = lw + o * 128 + oct * 16;   // contiguous 16 cells
        const float4 s0 = *(const float4*)(srow);
        const float4 s1 = *(const float4*)(srow + 4);
        const float4 s2 = *(const float4*)(srow + 8);
        const float4 s3 = *(const float4*)(srow + 12);
        const float4 w0 = *(const float4*)(wrow);
        const float4 w1 = *(const float4*)(wrow + 4);
        const float4 w2 = *(const float4*)(wrow + 8);
        const float4 w3 = *(const float4*)(wrow + 12);
        float v = 0.f;
        v += s0.x * w0.x; v += s0.y * w0.y; v += s0.z * w0.z; v += s0.w * w0.w;
        v += s1.x * w1.x; v += s1.y * w1.y; v += s1.z * w1.z; v += s1.w * w1.w;
        v += s2.x * w2.x; v += s2.y * w2.y; v += s2.z * w2.z; v += s2.w * w2.w;
        v += s3.x * w3.x; v += s3.y * w3.y; v += s3.z * w3.z; v += s3.w * w3.w;
        atomicAdd(&out[n * 200 + t * 2 + o], v);
    }
}

extern "C" void kernel_launch(void* const* d_in, const int* in_sizes, int n_in,
                              void* d_out, int out_size, void* d_ws, size_t ws_size,
                              hipStream_t stream) {
    const float* x   = (const float*)d_in[0];
    const float* w1  = (const float*)d_in[1];
    const float* w2  = (const float*)d_in[2];
    const float* lw  = (const float*)d_in[3];
    const float* wp1 = (const float*)d_in[4];
    const float* wp2 = (const float*)d_in[5];

    float* u1  = (float*)d_ws;           // 1,638,400 floats
    float* wl1 = u1 + 1638400;           //       512 floats
    float* wl2 = wl1 + 512;              //       544 floats
    float* out = (float*)d_out;          // (64,100,2) = 12800 floats

    k0_fold<<<100, 128, 0, stream>>>(w1, w2, wp1, wp2, wl1, wl2, out);
    k1<<<6400, 64, 0, stream>>>(x, wl1, u1);
    kf<<<512, 256, 0, stream>>>(u1, wl2, lw, out);
}